// Round 13
// baseline (161.449 us; speedup 1.0000x reference)
//
#include <hip/hip_runtime.h>
#include <cstddef>
#include <cstdint>

#define B_SZ    32768
#define NTAB    26
#define NROWS   200000

typedef __attribute__((ext_vector_type(8))) short short8v;
typedef __attribute__((ext_vector_type(4))) float f32x4;
typedef __attribute__((ext_vector_type(16))) float f32x16;

__device__ __forceinline__ ushort f2bf(float f) {
    uint32_t u = __builtin_bit_cast(uint32_t, f);
    u += 0x7FFFu + ((u >> 16) & 1u);
    return (ushort)(u >> 16);
}
__device__ __forceinline__ void stage16(const ushort* g, ushort* l) {
    __builtin_amdgcn_global_load_lds(
        (const __attribute__((address_space(1))) unsigned int*)g,
        (__attribute__((address_space(3))) unsigned int*)l, 16, 0, 0);
}

// All fp32->bf16 conversions (with K->Kp zero pad) in ONE kernel.
__global__ __launch_bounds__(256) void conv_all_k(
    const float* __restrict__ dense_x, const float* __restrict__ bw0,
    const float* __restrict__ tw0, const float* __restrict__ bw1,
    const float* __restrict__ bw2, const float* __restrict__ tw1,
    ushort* __restrict__ dense_pad, ushort* __restrict__ bw0p,
    ushort* __restrict__ tw0p, ushort* __restrict__ bw1c,
    ushort* __restrict__ bw2c, ushort* __restrict__ tw1c)
{
    const int gid = blockIdx.x * 256 + threadIdx.x;
    if (gid < 1048576) {
        int r = gid >> 5, k = gid & 31;
        dense_pad[gid] = (k < 13) ? f2bf(dense_x[r * 13 + k]) : (ushort)0;
    } else if (gid < 1064960) {
        int i = gid - 1048576; int r = i >> 5, k = i & 31;
        bw0p[i] = (k < 13) ? f2bf(bw0[r * 13 + k]) : (ushort)0;
    } else if (gid < 1277952) {
        int i = gid - 1064960; int r = i / 416, k = i - r * 416;
        tw0p[i] = (k < 415) ? f2bf(tw0[r * 415 + k]) : (ushort)0;
    } else if (gid < 1409024) {
        int i = gid - 1277952; bw1c[i] = f2bf(bw1[i]);
    } else if (gid < 1425408) {
        int i = gid - 1409024; bw2c[i] = f2bf(bw2[i]);
    } else if (gid < 1556480) {
        int i = gid - 1425408; tw1c[i] = f2bf(tw1[i]);
    }
}

// ---------------------------------------------------------------------------
// FULLY FUSED per-32-sample pipeline, weights read DIRECTLY global->VGPR
// (L2-resident, not cross-wave shared -> LDS staging was pure overhead).
// K-loops are barrier-free; syncs only at activation phase transitions.
// LDS 48 KB (R1 32 + R3 16) -> 3 blocks/CU, 12 waves.
// R1 = h0s(512) | Rt(424) | th0s(512); R3 = dense | h1s | scratch/red.
// ---------------------------------------------------------------------------
__global__ __launch_bounds__(256, 3) void fused_k(
    const ushort* __restrict__ dense_pad, const ushort* __restrict__ bw0p,
    const float* __restrict__ bb0, const ushort* __restrict__ bw1c,
    const float* __restrict__ bb1, const ushort* __restrict__ bw2c,
    const float* __restrict__ bb2,
    const float* __restrict__ emb, const int* __restrict__ indices,
    const ushort* __restrict__ tw0p, const float* __restrict__ tb0,
    const ushort* __restrict__ tw1c, const float* __restrict__ tb1,
    const float* __restrict__ tw2, const float* __restrict__ tb2,
    float* __restrict__ out)
{
    __shared__ __align__(16) ushort R1[32 * 512];      // 32 KB
    __shared__ __align__(16) ushort R3[32 * 256];      // 16 KB
    const int t = threadIdx.x;
    const int lane = t & 63, w = t >> 6;
    const int fr = lane & 15, j16 = lane >> 4;
    const int bBase = blockIdx.x * 32;

    // index loads to REGISTERS now; latency hides under the bottom MLP
    int ir0, ir1, ir2, ir3;
    ir0 = indices[(size_t)(t >> 5) * B_SZ + bBase + (t & 31)];
    ir1 = indices[(size_t)((256 + t) >> 5) * B_SZ + bBase + ((256 + t) & 31)];
    ir2 = indices[(size_t)((512 + t) >> 5) * B_SZ + bBase + ((512 + t) & 31)];
    ir3 = (t < 64) ? indices[(size_t)((768 + t) >> 5) * B_SZ + bBase + ((768 + t) & 31)] : 0;

    // dense tile (32x32) -> R3 (swizzled-source + swizzled-read pair)
    if (t < 128) {
        const int r = t >> 2, u = t & 3, us = u ^ ((r >> 1) & 3);
        stage16(dense_pad + (size_t)(bBase + r) * 32 + us * 8, &R3[t * 8]);
    }
    __syncthreads();

    // P0: h0 = relu(dense @ bw0^T + bb0), K=32, both channel halves
    f32x4 acc0[2][2][4] = {};
    {
        short8v a[2];
#pragma unroll
        for (int m = 0; m < 2; ++m) {
            const int r = m * 16 + fr;
            a[m] = *(const short8v*)&R3[r * 32 + (j16 ^ ((r >> 1) & 3)) * 8];
        }
#pragma unroll
        for (int hh = 0; hh < 2; ++hh) {
            short8v b[4];
#pragma unroll
            for (int n = 0; n < 4; ++n) {
                const int lr = hh * 256 + w * 64 + n * 16 + fr;
                b[n] = *(const short8v*)&bw0p[(size_t)lr * 32 + j16 * 8];
            }
            __builtin_amdgcn_s_setprio(1);
#pragma unroll
            for (int m = 0; m < 2; ++m)
#pragma unroll
                for (int n = 0; n < 4; ++n)
                    acc0[hh][m][n] = __builtin_amdgcn_mfma_f32_16x16x32_bf16(b[n], a[m], acc0[hh][m][n], 0, 0, 0);
            __builtin_amdgcn_s_setprio(0);
        }
    }
    // P0 epilogue -> R1 as h0s (stride 512, swizzle by sample&7)
#pragma unroll
    for (int hh = 0; hh < 2; ++hh)
#pragma unroll
    for (int n = 0; n < 4; ++n) {
        const int ch = hh * 256 + w * 64 + n * 16 + j16 * 4;
        const float4 bv = *(const float4*)&bb0[ch];
#pragma unroll
        for (int m = 0; m < 2; ++m) {
            const int s = m * 16 + fr;
            ushort4 o;
            o.x = f2bf(fmaxf(acc0[hh][m][n][0] + bv.x, 0.f));
            o.y = f2bf(fmaxf(acc0[hh][m][n][1] + bv.y, 0.f));
            o.z = f2bf(fmaxf(acc0[hh][m][n][2] + bv.z, 0.f));
            o.w = f2bf(fmaxf(acc0[hh][m][n][3] + bv.w, 0.f));
            const int u = ch >> 3, su = u ^ (s & 7);
            *(ushort4*)&R1[s * 512 + su * 8 + (ch & 7)] = o;
        }
    }
    __syncthreads();

    // P1: h1 = relu(h0 @ bw1^T + bb1), K=512 -- barrier-free K-loop
    f32x4 acc1[2][4] = {};
    for (int kt = 0; kt < 512; kt += 32) {
        short8v a[2], b[4];
#pragma unroll
        for (int m = 0; m < 2; ++m) {
            const int s = m * 16 + fr;
            const int u = (kt >> 3) + j16, su = u ^ (s & 7);
            a[m] = *(const short8v*)&R1[s * 512 + su * 8];
        }
#pragma unroll
        for (int n = 0; n < 4; ++n) {
            const int lr = w * 64 + n * 16 + fr;
            b[n] = *(const short8v*)&bw1c[(size_t)lr * 512 + kt + j16 * 8];
        }
        __builtin_amdgcn_s_setprio(1);
#pragma unroll
        for (int m = 0; m < 2; ++m)
#pragma unroll
            for (int n = 0; n < 4; ++n)
                acc1[m][n] = __builtin_amdgcn_mfma_f32_16x16x32_bf16(b[n], a[m], acc1[m][n], 0, 0, 0);
        __builtin_amdgcn_s_setprio(0);
    }
    // P1 epilogue -> R3 as h1s (R3-dense readers all finished before h0s sync)
#pragma unroll
    for (int n = 0; n < 4; ++n) {
        const int ch = w * 64 + n * 16 + j16 * 4;
        const float4 bv = *(const float4*)&bb1[ch];
#pragma unroll
        for (int m = 0; m < 2; ++m) {
            const int s = m * 16 + fr;
            ushort4 o;
            o.x = f2bf(fmaxf(acc1[m][n][0] + bv.x, 0.f));
            o.y = f2bf(fmaxf(acc1[m][n][1] + bv.y, 0.f));
            o.z = f2bf(fmaxf(acc1[m][n][2] + bv.z, 0.f));
            o.w = f2bf(fmaxf(acc1[m][n][3] + bv.w, 0.f));
            const int u = ch >> 3, su = u ^ (s & 7);
            *(ushort4*)&R3[s * 256 + su * 8 + (ch & 7)] = o;
        }
    }
    __syncthreads();

    // P2: x_bot = relu(h1 @ bw2^T + bb2), K=256 -- barrier-free
    f32x4 acc2[2] = {};
    for (int kt = 0; kt < 256; kt += 32) {
        short8v a[2], b;
#pragma unroll
        for (int m = 0; m < 2; ++m) {
            const int s = m * 16 + fr;
            const int u = (kt >> 3) + j16, su = u ^ (s & 7);
            a[m] = *(const short8v*)&R3[s * 256 + su * 8];
        }
        {
            const int lr = w * 16 + fr;
            b = *(const short8v*)&bw2c[(size_t)lr * 256 + kt + j16 * 8];
        }
#pragma unroll
        for (int m = 0; m < 2; ++m)
            acc2[m] = __builtin_amdgcn_mfma_f32_16x16x32_bf16(b, a[m], acc2[m], 0, 0, 0);
    }
    __syncthreads();   // all h1s reads done before scratch overwrites R3

    // P2 epilogue: x_bot -> R1 as Rt[:, 0:64]; zero col 415; dump indices
    {
        const int ch = w * 16 + j16 * 4;
        const float4 bv = *(const float4*)&bb2[ch];
#pragma unroll
        for (int m = 0; m < 2; ++m) {
            const int s = m * 16 + fr;
            ushort4 o;
            o.x = f2bf(fmaxf(acc2[m][0] + bv.x, 0.f));
            o.y = f2bf(fmaxf(acc2[m][1] + bv.y, 0.f));
            o.z = f2bf(fmaxf(acc2[m][2] + bv.z, 0.f));
            o.w = f2bf(fmaxf(acc2[m][3] + bv.w, 0.f));
            *(ushort4*)&R1[s * 424 + ch] = o;
        }
    }
    if (t < 32) R1[t * 424 + 415] = 0;
    {
        int* sc = (int*)R3;
        sc[t] = ir0; sc[256 + t] = ir1; sc[512 + t] = ir2;
        if (t < 64) sc[768 + t] = ir3;
    }
    __syncthreads();

    // Gram: per wave-sample, Z = T.T^T via 4x mfma_32x32x16 (A == B).
    {
        const int* sc = (const int*)R3;
        const int r32 = lane & 31, half = lane >> 5;
        for (int it = 0; it < 8; ++it) {
            const int s = it * 4 + w;
            short8v tf[4];
            if (r32 == 0) {
#pragma unroll
                for (int kq = 0; kq < 4; ++kq)
                    tf[kq] = *(const short8v*)&R1[s * 424 + kq * 16 + half * 8];
            } else if (r32 <= 26) {
                const int idxv = sc[(r32 - 1) * 32 + s];
                const float* rp = emb + ((size_t)(r32 - 1) * NROWS + (size_t)idxv) * 64 + half * 8;
#pragma unroll
                for (int kq = 0; kq < 4; ++kq) {
                    const f32x4 x = *(const f32x4*)&rp[kq * 16];
                    const f32x4 y = *(const f32x4*)&rp[kq * 16 + 4];
                    short8v v;
                    v[0] = (short)f2bf(x[0]); v[1] = (short)f2bf(x[1]);
                    v[2] = (short)f2bf(x[2]); v[3] = (short)f2bf(x[3]);
                    v[4] = (short)f2bf(y[0]); v[5] = (short)f2bf(y[1]);
                    v[6] = (short)f2bf(y[2]); v[7] = (short)f2bf(y[3]);
                    tf[kq] = v;
                }
            } else {
#pragma unroll
                for (int kq = 0; kq < 4; ++kq) tf[kq] = (short8v)0;
            }
            f32x16 c = {};
#pragma unroll
            for (int kq = 0; kq < 4; ++kq)
                c = __builtin_amdgcn_mfma_f32_32x32x16_bf16(tf[kq], tf[kq], c, 0, 0, 0);
            // strict lower triangle: row=(reg&3)+8*(reg>>2)+4*half, col=r32
            // (writes cols 64..414; reads were cols 0..63 -- disjoint, no sync)
#pragma unroll
            for (int reg = 0; reg < 16; ++reg) {
                const int r = (reg & 3) + 8 * (reg >> 2) + 4 * half;
                if (r < 27 && r32 < r)
                    R1[s * 424 + 64 + (r * (r - 1)) / 2 + r32] = f2bf(c[reg]);
            }
        }
    }
    __syncthreads();

    // phase A: th0 = relu(R @ tw0^T + tb0), K=416 -- barrier-free
    f32x4 accA[2][2][4] = {};
    for (int kt = 0; kt < 416; kt += 32) {
        short8v a[2];
#pragma unroll
        for (int m = 0; m < 2; ++m) {
            const int s = m * 16 + fr;
            a[m] = *(const short8v*)&R1[s * 424 + ((kt >> 3) + j16) * 8];
        }
#pragma unroll
        for (int hh = 0; hh < 2; ++hh) {
            short8v b[4];
#pragma unroll
            for (int n = 0; n < 4; ++n) {
                const int lr = hh * 256 + w * 64 + n * 16 + fr;
                b[n] = *(const short8v*)&tw0p[(size_t)lr * 416 + kt + j16 * 8];
            }
            __builtin_amdgcn_s_setprio(1);
#pragma unroll
            for (int m = 0; m < 2; ++m)
#pragma unroll
                for (int n = 0; n < 4; ++n)
                    accA[hh][m][n] = __builtin_amdgcn_mfma_f32_16x16x32_bf16(b[n], a[m], accA[hh][m][n], 0, 0, 0);
            __builtin_amdgcn_s_setprio(0);
        }
    }
    __syncthreads();   // all Rt reads done before th0s overwrite
    // phase A epilogue: th0s into R1 (stride 512)
#pragma unroll
    for (int hh = 0; hh < 2; ++hh)
#pragma unroll
    for (int n = 0; n < 4; ++n) {
        const int ch = hh * 256 + w * 64 + n * 16 + j16 * 4;
        const float4 bv = *(const float4*)&tb0[ch];
#pragma unroll
        for (int m = 0; m < 2; ++m) {
            const int s = m * 16 + fr;
            ushort4 o;
            o.x = f2bf(fmaxf(accA[hh][m][n][0] + bv.x, 0.f));
            o.y = f2bf(fmaxf(accA[hh][m][n][1] + bv.y, 0.f));
            o.z = f2bf(fmaxf(accA[hh][m][n][2] + bv.z, 0.f));
            o.w = f2bf(fmaxf(accA[hh][m][n][3] + bv.w, 0.f));
            const int u = ch >> 3, su = u ^ (s & 7);
            *(ushort4*)&R1[s * 512 + su * 8 + (ch & 7)] = o;
        }
    }
    __syncthreads();

    // phase B: th1 = relu(th0 @ tw1^T + tb1), K=512 -- barrier-free
    f32x4 accB[2][4] = {};
    for (int kt = 0; kt < 512; kt += 32) {
        short8v a[2], b[4];
#pragma unroll
        for (int m = 0; m < 2; ++m) {
            const int s = m * 16 + fr;
            const int u = (kt >> 3) + j16, su = u ^ (s & 7);
            a[m] = *(const short8v*)&R1[s * 512 + su * 8];
        }
#pragma unroll
        for (int n = 0; n < 4; ++n) {
            const int lr = w * 64 + n * 16 + fr;
            b[n] = *(const short8v*)&tw1c[(size_t)lr * 512 + kt + j16 * 8];
        }
        __builtin_amdgcn_s_setprio(1);
#pragma unroll
        for (int m = 0; m < 2; ++m)
#pragma unroll
            for (int n = 0; n < 4; ++n)
                accB[m][n] = __builtin_amdgcn_mfma_f32_16x16x32_bf16(b[n], a[m], accB[m][n], 0, 0, 0);
        __builtin_amdgcn_s_setprio(0);
    }

    // phase C: out = sigmoid( relu(th1) . tw2 + tb2 )
    float* red = (float*)R3;
    float part[2] = {0.f, 0.f};
#pragma unroll
    for (int n = 0; n < 4; ++n) {
        const int ch = w * 64 + n * 16 + j16 * 4;
        const float4 bv = *(const float4*)&tb1[ch];
        const float4 wv = *(const float4*)&tw2[ch];
#pragma unroll
        for (int m = 0; m < 2; ++m) {
            part[m] += fmaxf(accB[m][n][0] + bv.x, 0.f) * wv.x
                     + fmaxf(accB[m][n][1] + bv.y, 0.f) * wv.y
                     + fmaxf(accB[m][n][2] + bv.z, 0.f) * wv.z
                     + fmaxf(accB[m][n][3] + bv.w, 0.f) * wv.w;
        }
    }
#pragma unroll
    for (int m = 0; m < 2; ++m) {
        float v = part[m];
        v += __shfl_xor(v, 16, 64);
        v += __shfl_xor(v, 32, 64);
        if (lane < 16) red[w * 32 + m * 16 + fr] = v;
    }
    __syncthreads();
    if (t < 32) {
        const float sm = red[t] + red[32 + t] + red[64 + t] + red[96 + t];
        out[bBase + t] = 1.f / (1.f + expf(-(sm + tb2[0])));
    }
}

extern "C" void kernel_launch(void* const* d_in, const int* in_sizes, int n_in,
                              void* d_out, int out_size, void* d_ws, size_t ws_size,
                              hipStream_t stream)
{
    (void)in_sizes; (void)n_in; (void)out_size; (void)ws_size;
    const float* dense_x = (const float*)d_in[0];
    const int*   indices = (const int*)d_in[1];
    const float* emb     = (const float*)d_in[2];
    const float* bw0 = (const float*)d_in[3];
    const float* bb0 = (const float*)d_in[4];
    const float* bw1 = (const float*)d_in[5];
    const float* bb1 = (const float*)d_in[6];
    const float* bw2 = (const float*)d_in[7];
    const float* bb2 = (const float*)d_in[8];
    const float* tw0 = (const float*)d_in[9];
    const float* tb0 = (const float*)d_in[10];
    const float* tw1 = (const float*)d_in[11];
    const float* tb1 = (const float*)d_in[12];
    const float* tw2 = (const float*)d_in[13];
    const float* tb2 = (const float*)d_in[14];
    float* out = (float*)d_out;

    ushort* ws16      = (ushort*)d_ws;
    ushort* dense_pad = ws16;                              // B x 32
    ushort* bw0p      = dense_pad + (size_t)B_SZ * 32;     // 512 x 32
    ushort* tw0p      = bw0p + 512 * 32;                   // 512 x 416
    ushort* bw1c      = tw0p + 512 * 416;                  // 256 x 512
    ushort* bw2c      = bw1c + 256 * 512;                  // 64 x 256
    ushort* tw1c      = bw2c + 64 * 256;                   // 256 x 512

    conv_all_k<<<dim3(6080), dim3(256), 0, stream>>>(
        dense_x, bw0, tw0, bw1, bw2, tw1,
        dense_pad, bw0p, tw0p, bw1c, bw2c, tw1c);

    fused_k<<<dim3(B_SZ / 32), dim3(256), 0, stream>>>(
        dense_pad, bw0p, bb0, bw1c, bb1, bw2c, bb2,
        emb, indices, tw0p, tb0, tw1c, tb1, tw2, tb2, out);
}

// Round 14
// 116.362 us; speedup vs baseline: 1.3875x; 1.3875x over previous
//
#include <hip/hip_runtime.h>
#include <cstddef>
#include <cstdint>

#define B_SZ    32768
#define NTAB    26
#define NROWS   200000

typedef __attribute__((ext_vector_type(8))) short short8v;
typedef __attribute__((ext_vector_type(4))) float f32x4;
typedef __attribute__((ext_vector_type(16))) float f32x16;

__device__ __forceinline__ ushort f2bf(float f) {
    uint32_t u = __builtin_bit_cast(uint32_t, f);
    u += 0x7FFFu + ((u >> 16) & 1u);
    return (ushort)(u >> 16);
}
__device__ __forceinline__ void stage16(const ushort* g, ushort* l) {
    __builtin_amdgcn_global_load_lds(
        (const __attribute__((address_space(1))) unsigned int*)g,
        (__attribute__((address_space(3))) unsigned int*)l, 16, 0, 0);
}

// All fp32->bf16 conversions (with K->Kp zero pad) in ONE kernel.
__global__ __launch_bounds__(256) void conv_all_k(
    const float* __restrict__ dense_x, const float* __restrict__ bw0,
    const float* __restrict__ tw0, const float* __restrict__ bw1,
    const float* __restrict__ bw2, const float* __restrict__ tw1,
    ushort* __restrict__ dense_pad, ushort* __restrict__ bw0p,
    ushort* __restrict__ tw0p, ushort* __restrict__ bw1c,
    ushort* __restrict__ bw2c, ushort* __restrict__ tw1c)
{
    const int gid = blockIdx.x * 256 + threadIdx.x;
    if (gid < 1048576) {
        int r = gid >> 5, k = gid & 31;
        dense_pad[gid] = (k < 13) ? f2bf(dense_x[r * 13 + k]) : (ushort)0;
    } else if (gid < 1064960) {
        int i = gid - 1048576; int r = i >> 5, k = i & 31;
        bw0p[i] = (k < 13) ? f2bf(bw0[r * 13 + k]) : (ushort)0;
    } else if (gid < 1277952) {
        int i = gid - 1064960; int r = i / 416, k = i - r * 416;
        tw0p[i] = (k < 415) ? f2bf(tw0[r * 415 + k]) : (ushort)0;
    } else if (gid < 1409024) {
        int i = gid - 1277952; bw1c[i] = f2bf(bw1[i]);
    } else if (gid < 1425408) {
        int i = gid - 1409024; bw2c[i] = f2bf(bw2[i]);
    } else if (gid < 1556480) {
        int i = gid - 1425408; tw1c[i] = f2bf(tw1[i]);
    }
}

// ---------------------------------------------------------------------------
// FULLY FUSED per-64-sample pipeline (512 threads, 8 waves = 2 wr x 4 wc):
//   bot: 13(->32) -> 512 -> 256 -> 64 (x_bot in LDS)
//   gather 26 emb rows/sample + Gram Z = T.T^T (32x32x16 MFMA, A==B)
//   top: 415(->416) -> 512 -> 256 -> dot+sigmoid
// Weight LDS staging, double-wide (32 KB/drain). 64 samples/block halves
// the per-sample weight L2 traffic and drain count vs 32-sample blocks.
// LDS 128 KB -> 1 block/CU (8 waves).
// R1(64KB) = h0s(512) | Rt(424) | th0s(512); R3(32KB) = dense | h1s | scratch.
// ---------------------------------------------------------------------------
__global__ __launch_bounds__(512, 2) void fused_k(
    const ushort* __restrict__ dense_pad, const ushort* __restrict__ bw0p,
    const float* __restrict__ bb0, const ushort* __restrict__ bw1c,
    const float* __restrict__ bb1, const ushort* __restrict__ bw2c,
    const float* __restrict__ bb2,
    const float* __restrict__ emb, const int* __restrict__ indices,
    const ushort* __restrict__ tw0p, const float* __restrict__ tb0,
    const ushort* __restrict__ tw1c, const float* __restrict__ tb1,
    const float* __restrict__ tw2, const float* __restrict__ tb2,
    float* __restrict__ out)
{
    __shared__ __align__(16) ushort R1[64 * 512];      // 64 KB
    __shared__ __align__(16) ushort Wst[2][256 * 32];  // 2 x 16 KB
    __shared__ __align__(16) ushort R3[64 * 256];      // 32 KB
    const int t = threadIdx.x;
    const int lane = t & 63, w = t >> 6;
    const int wr = w >> 2, wc = w & 3;
    const int fr = lane & 15, j16 = lane >> 4;
    const int bBase = blockIdx.x * 64;

    // index loads to REGISTERS now; latency hides under the bottom MLP
    int ir0, ir1, ir2, ir3;
    ir0 = indices[(size_t)(t >> 6) * B_SZ + bBase + (t & 63)];
    ir1 = indices[(size_t)((512 + t) >> 6) * B_SZ + bBase + ((512 + t) & 63)];
    ir2 = indices[(size_t)((1024 + t) >> 6) * B_SZ + bBase + ((1024 + t) & 63)];
    ir3 = (t < 128) ? indices[(size_t)((1536 + t) >> 6) * B_SZ + bBase + ((1536 + t) & 63)] : 0;

    // prologue: dense tile (64x32) -> R3; all of bw0p -> Wst[0]+Wst[1]
    if (t < 256) {
        const int r = t >> 2, u = t & 3, us = u ^ ((r >> 1) & 3);
        stage16(dense_pad + (size_t)(bBase + r) * 32 + us * 8, &R3[t * 8]);
    }
#pragma unroll
    for (int i = 0; i < 2; ++i) {
        const int idx = i * 512 + t;
        const int r = idx >> 2, u = idx & 3, us = u ^ ((r >> 1) & 3);
        stage16(bw0p + (size_t)r * 32 + us * 8, &Wst[0][idx * 8]);
        stage16(bw0p + (size_t)(256 + r) * 32 + us * 8, &Wst[1][idx * 8]);
    }
    __syncthreads();

    // P0: h0 = relu(dense @ bw0^T + bb0), K=32; wave covers 32 samp x 128 ch
    f32x4 acc0[2][8] = {};
    {
        short8v a[2], b[8];
#pragma unroll
        for (int m = 0; m < 2; ++m) {
            const int r = wr * 32 + m * 16 + fr;
            a[m] = *(const short8v*)&R3[r * 32 + (j16 ^ ((r >> 1) & 3)) * 8];
        }
#pragma unroll
        for (int n = 0; n < 8; ++n) {
            const int lr = wc * 128 + n * 16 + fr;
            const int lb = lr & 255;
            b[n] = *(const short8v*)&Wst[lr >> 8][lb * 32 + (j16 ^ ((lb >> 1) & 3)) * 8];
        }
        __builtin_amdgcn_s_setprio(1);
#pragma unroll
        for (int m = 0; m < 2; ++m)
#pragma unroll
            for (int n = 0; n < 8; ++n)
                acc0[m][n] = __builtin_amdgcn_mfma_f32_16x16x32_bf16(b[n], a[m], acc0[m][n], 0, 0, 0);
        __builtin_amdgcn_s_setprio(0);
    }
    __syncthreads();   // P0 Wst + R3-dense reads complete

    // pre-stage P1 pair (bw1c kt=0 -> Wst[0], kt=32 -> Wst[1])
#pragma unroll
    for (int i = 0; i < 2; ++i) {
        const int idx = i * 512 + t;
        const int r = idx >> 2, u = idx & 3, us = u ^ ((r >> 1) & 3);
        stage16(bw1c + (size_t)r * 512 + us * 8, &Wst[0][idx * 8]);
        stage16(bw1c + (size_t)r * 512 + 32 + us * 8, &Wst[1][idx * 8]);
    }
    // P0 epilogue -> R1 as h0s (stride 512, swizzle by sample&7)
#pragma unroll
    for (int n = 0; n < 8; ++n) {
        const int ch = wc * 128 + n * 16 + j16 * 4;
        const float4 bv = *(const float4*)&bb0[ch];
#pragma unroll
        for (int m = 0; m < 2; ++m) {
            const int s = wr * 32 + m * 16 + fr;
            ushort4 o;
            o.x = f2bf(fmaxf(acc0[m][n][0] + bv.x, 0.f));
            o.y = f2bf(fmaxf(acc0[m][n][1] + bv.y, 0.f));
            o.z = f2bf(fmaxf(acc0[m][n][2] + bv.z, 0.f));
            o.w = f2bf(fmaxf(acc0[m][n][3] + bv.w, 0.f));
            const int u = ch >> 3, su = u ^ (s & 7);
            *(ushort4*)&R1[s * 512 + su * 8 + (ch & 7)] = o;
        }
    }
    __syncthreads();

    // P1: h1 = relu(h0 @ bw1^T + bb1), K=512, 8 iters x 64k; wave: 32s x 64ch
    f32x4 acc1[2][4] = {};
    for (int i8 = 0; i8 < 8; ++i8) {
#pragma unroll
        for (int half = 0; half < 2; ++half) {
            const int kt = i8 * 64 + half * 32;
            short8v a[2], b[4];
#pragma unroll
            for (int m = 0; m < 2; ++m) {
                const int s = wr * 32 + m * 16 + fr;
                const int u = (kt >> 3) + j16, su = u ^ (s & 7);
                a[m] = *(const short8v*)&R1[s * 512 + su * 8];
            }
#pragma unroll
            for (int n = 0; n < 4; ++n) {
                const int lr = wc * 64 + n * 16 + fr;
                b[n] = *(const short8v*)&Wst[half][lr * 32 + (j16 ^ ((lr >> 1) & 3)) * 8];
            }
            __builtin_amdgcn_s_setprio(1);
#pragma unroll
            for (int m = 0; m < 2; ++m)
#pragma unroll
                for (int n = 0; n < 4; ++n)
                    acc1[m][n] = __builtin_amdgcn_mfma_f32_16x16x32_bf16(b[n], a[m], acc1[m][n], 0, 0, 0);
            __builtin_amdgcn_s_setprio(0);
        }
        __syncthreads();
        if (i8 < 7) {
            const int kt2 = (i8 + 1) * 64;
#pragma unroll
            for (int i = 0; i < 2; ++i) {
                const int idx = i * 512 + t;
                const int r = idx >> 2, u = idx & 3, us = u ^ ((r >> 1) & 3);
                stage16(bw1c + (size_t)r * 512 + kt2 + us * 8, &Wst[0][idx * 8]);
                stage16(bw1c + (size_t)r * 512 + kt2 + 32 + us * 8, &Wst[1][idx * 8]);
            }
            __syncthreads();
        }
    }
    // pre-stage P2 pair (bw2c 64 rows x 32k each)
    if (t < 256) {
        const int r = t >> 2, u = t & 3, us = u ^ ((r >> 1) & 3);
        stage16(bw2c + (size_t)r * 256 + us * 8, &Wst[0][t * 8]);
        stage16(bw2c + (size_t)r * 256 + 32 + us * 8, &Wst[1][t * 8]);
    }
    // P1 epilogue -> R3 as h1s (stride 256, swizzle)
#pragma unroll
    for (int n = 0; n < 4; ++n) {
        const int ch = wc * 64 + n * 16 + j16 * 4;
        const float4 bv = *(const float4*)&bb1[ch];
#pragma unroll
        for (int m = 0; m < 2; ++m) {
            const int s = wr * 32 + m * 16 + fr;
            ushort4 o;
            o.x = f2bf(fmaxf(acc1[m][n][0] + bv.x, 0.f));
            o.y = f2bf(fmaxf(acc1[m][n][1] + bv.y, 0.f));
            o.z = f2bf(fmaxf(acc1[m][n][2] + bv.z, 0.f));
            o.w = f2bf(fmaxf(acc1[m][n][3] + bv.w, 0.f));
            const int u = ch >> 3, su = u ^ (s & 7);
            *(ushort4*)&R3[s * 256 + su * 8 + (ch & 7)] = o;
        }
    }
    __syncthreads();

    // P2: x_bot = relu(h1 @ bw2^T + bb2), K=256, 4 iters x 64k; wave: 32s x 16ch
    f32x4 acc2[2] = {};
    for (int i8 = 0; i8 < 4; ++i8) {
#pragma unroll
        for (int half = 0; half < 2; ++half) {
            const int kt = i8 * 64 + half * 32;
            short8v a[2], b;
#pragma unroll
            for (int m = 0; m < 2; ++m) {
                const int s = wr * 32 + m * 16 + fr;
                const int u = (kt >> 3) + j16, su = u ^ (s & 7);
                a[m] = *(const short8v*)&R3[s * 256 + su * 8];
            }
            {
                const int lr = wc * 16 + fr;
                b = *(const short8v*)&Wst[half][lr * 32 + (j16 ^ ((lr >> 1) & 3)) * 8];
            }
#pragma unroll
            for (int m = 0; m < 2; ++m)
                acc2[m] = __builtin_amdgcn_mfma_f32_16x16x32_bf16(b, a[m], acc2[m], 0, 0, 0);
        }
        __syncthreads();
        if (i8 < 3) {
            const int kt2 = (i8 + 1) * 64;
            if (t < 256) {
                const int r = t >> 2, u = t & 3, us = u ^ ((r >> 1) & 3);
                stage16(bw2c + (size_t)r * 256 + kt2 + us * 8, &Wst[0][t * 8]);
                stage16(bw2c + (size_t)r * 256 + kt2 + 32 + us * 8, &Wst[1][t * 8]);
            }
            __syncthreads();
        }
    }
    // P2 epilogue: x_bot -> R1 as Rt[:, 0:64]; zero col 415; dump indices;
    // pre-stage top-A kt=0 pair
    {
        const int ch = wc * 16 + j16 * 4;
        const float4 bv = *(const float4*)&bb2[ch];
#pragma unroll
        for (int m = 0; m < 2; ++m) {
            const int s = wr * 32 + m * 16 + fr;
            ushort4 o;
            o.x = f2bf(fmaxf(acc2[m][0] + bv.x, 0.f));
            o.y = f2bf(fmaxf(acc2[m][1] + bv.y, 0.f));
            o.z = f2bf(fmaxf(acc2[m][2] + bv.z, 0.f));
            o.w = f2bf(fmaxf(acc2[m][3] + bv.w, 0.f));
            *(ushort4*)&R1[s * 424 + ch] = o;
        }
    }
    if (t < 64) R1[t * 424 + 415] = 0;
    {
        int* sc = (int*)R3;
        sc[t] = ir0; sc[512 + t] = ir1; sc[1024 + t] = ir2;
        if (t < 128) sc[1536 + t] = ir3;
    }
#pragma unroll
    for (int i = 0; i < 2; ++i) {
        const int idx = i * 512 + t;
        const int r = idx >> 2, u = idx & 3, us = u ^ ((r >> 1) & 3);
        stage16(tw0p + (size_t)r * 416 + us * 8, &Wst[0][idx * 8]);
        stage16(tw0p + (size_t)(256 + r) * 416 + us * 8, &Wst[1][idx * 8]);
    }
    __syncthreads();

    // Gram: per wave-sample, Z = T.T^T via 4x mfma_32x32x16 (A == B).
    {
        const int* sc = (const int*)R3;
        const int r32 = lane & 31, half = lane >> 5;
        for (int it = 0; it < 8; ++it) {
            const int s = it * 8 + w;
            short8v tf[4];
            if (r32 == 0) {
#pragma unroll
                for (int kq = 0; kq < 4; ++kq)
                    tf[kq] = *(const short8v*)&R1[s * 424 + kq * 16 + half * 8];
            } else if (r32 <= 26) {
                const int idxv = sc[(r32 - 1) * 64 + s];
                const float* rp = emb + ((size_t)(r32 - 1) * NROWS + (size_t)idxv) * 64 + half * 8;
#pragma unroll
                for (int kq = 0; kq < 4; ++kq) {
                    const f32x4 x = *(const f32x4*)&rp[kq * 16];
                    const f32x4 y = *(const f32x4*)&rp[kq * 16 + 4];
                    short8v v;
                    v[0] = (short)f2bf(x[0]); v[1] = (short)f2bf(x[1]);
                    v[2] = (short)f2bf(x[2]); v[3] = (short)f2bf(x[3]);
                    v[4] = (short)f2bf(y[0]); v[5] = (short)f2bf(y[1]);
                    v[6] = (short)f2bf(y[2]); v[7] = (short)f2bf(y[3]);
                    tf[kq] = v;
                }
            } else {
#pragma unroll
                for (int kq = 0; kq < 4; ++kq) tf[kq] = (short8v)0;
            }
            f32x16 c = {};
#pragma unroll
            for (int kq = 0; kq < 4; ++kq)
                c = __builtin_amdgcn_mfma_f32_32x32x16_bf16(tf[kq], tf[kq], c, 0, 0, 0);
            // strict lower triangle: row=(reg&3)+8*(reg>>2)+4*half, col=r32
#pragma unroll
            for (int reg = 0; reg < 16; ++reg) {
                const int r = (reg & 3) + 8 * (reg >> 2) + 4 * half;
                if (r < 27 && r32 < r)
                    R1[s * 424 + 64 + (r * (r - 1)) / 2 + r32] = f2bf(c[reg]);
            }
        }
    }
    __syncthreads();

    // phase A: th0 = relu(R @ tw0^T + tb0), K=416, 13 iters; wave: 32s x 128ch
    f32x4 accA[2][8] = {};
    for (int kt_i = 0; kt_i < 13; ++kt_i) {
        const int kt = kt_i * 32;
        short8v a[2], b[8];
#pragma unroll
        for (int m = 0; m < 2; ++m) {
            const int s = wr * 32 + m * 16 + fr;
            a[m] = *(const short8v*)&R1[s * 424 + ((kt >> 3) + j16) * 8];
        }
#pragma unroll
        for (int n = 0; n < 8; ++n) {
            const int lr = wc * 128 + n * 16 + fr;
            const int lb = lr & 255;
            b[n] = *(const short8v*)&Wst[lr >> 8][lb * 32 + (j16 ^ ((lb >> 1) & 3)) * 8];
        }
        __builtin_amdgcn_s_setprio(1);
#pragma unroll
        for (int m = 0; m < 2; ++m)
#pragma unroll
            for (int n = 0; n < 8; ++n)
                accA[m][n] = __builtin_amdgcn_mfma_f32_16x16x32_bf16(b[n], a[m], accA[m][n], 0, 0, 0);
        __builtin_amdgcn_s_setprio(0);
        __syncthreads();
        if (kt_i < 12) {
            const int kt2 = kt + 32;
#pragma unroll
            for (int i = 0; i < 2; ++i) {
                const int idx = i * 512 + t;
                const int r = idx >> 2, u = idx & 3, us = u ^ ((r >> 1) & 3);
                stage16(tw0p + (size_t)r * 416 + kt2 + us * 8, &Wst[0][idx * 8]);
                stage16(tw0p + (size_t)(256 + r) * 416 + kt2 + us * 8, &Wst[1][idx * 8]);
            }
            __syncthreads();
        }
    }
    // pre-stage phase-B pair (tw1c kt=0 -> Wst[0], kt=32 -> Wst[1])
#pragma unroll
    for (int i = 0; i < 2; ++i) {
        const int idx = i * 512 + t;
        const int r = idx >> 2, u = idx & 3, us = u ^ ((r >> 1) & 3);
        stage16(tw1c + (size_t)r * 512 + us * 8, &Wst[0][idx * 8]);
        stage16(tw1c + (size_t)r * 512 + 32 + us * 8, &Wst[1][idx * 8]);
    }
    // phase A epilogue: th0s into R1 (stride 512; Rt dead)
#pragma unroll
    for (int n = 0; n < 8; ++n) {
        const int ch = wc * 128 + n * 16 + j16 * 4;
        const float4 bv = *(const float4*)&tb0[ch];
#pragma unroll
        for (int m = 0; m < 2; ++m) {
            const int s = wr * 32 + m * 16 + fr;
            ushort4 o;
            o.x = f2bf(fmaxf(accA[m][n][0] + bv.x, 0.f));
            o.y = f2bf(fmaxf(accA[m][n][1] + bv.y, 0.f));
            o.z = f2bf(fmaxf(accA[m][n][2] + bv.z, 0.f));
            o.w = f2bf(fmaxf(accA[m][n][3] + bv.w, 0.f));
            const int u = ch >> 3, su = u ^ (s & 7);
            *(ushort4*)&R1[s * 512 + su * 8 + (ch & 7)] = o;
        }
    }
    __syncthreads();

    // phase B: th1 = relu(th0 @ tw1^T + tb1), K=512, 8 iters x 64k
    f32x4 accB[2][4] = {};
    for (int i8 = 0; i8 < 8; ++i8) {
#pragma unroll
        for (int half = 0; half < 2; ++half) {
            const int kt = i8 * 64 + half * 32;
            short8v a[2], b[4];
#pragma unroll
            for (int m = 0; m < 2; ++m) {
                const int s = wr * 32 + m * 16 + fr;
                const int u = (kt >> 3) + j16, su = u ^ (s & 7);
                a[m] = *(const short8v*)&R1[s * 512 + su * 8];
            }
#pragma unroll
            for (int n = 0; n < 4; ++n) {
                const int lr = wc * 64 + n * 16 + fr;
                b[n] = *(const short8v*)&Wst[half][lr * 32 + (j16 ^ ((lr >> 1) & 3)) * 8];
            }
            __builtin_amdgcn_s_setprio(1);
#pragma unroll
            for (int m = 0; m < 2; ++m)
#pragma unroll
                for (int n = 0; n < 4; ++n)
                    accB[m][n] = __builtin_amdgcn_mfma_f32_16x16x32_bf16(b[n], a[m], accB[m][n], 0, 0, 0);
            __builtin_amdgcn_s_setprio(0);
        }
        __syncthreads();
        if (i8 < 7) {
            const int kt2 = (i8 + 1) * 64;
#pragma unroll
            for (int i = 0; i < 2; ++i) {
                const int idx = i * 512 + t;
                const int r = idx >> 2, u = idx & 3, us = u ^ ((r >> 1) & 3);
                stage16(tw1c + (size_t)r * 512 + kt2 + us * 8, &Wst[0][idx * 8]);
                stage16(tw1c + (size_t)r * 512 + kt2 + 32 + us * 8, &Wst[1][idx * 8]);
            }
            __syncthreads();
        }
    }

    // phase C: out = sigmoid( relu(th1) . tw2 + tb2 )
    float* red = (float*)R3;
    float part[2] = {0.f, 0.f};
#pragma unroll
    for (int n = 0; n < 4; ++n) {
        const int ch = wc * 64 + n * 16 + j16 * 4;
        const float4 bv = *(const float4*)&tb1[ch];
        const float4 wv = *(const float4*)&tw2[ch];
#pragma unroll
        for (int m = 0; m < 2; ++m) {
            part[m] += fmaxf(accB[m][n][0] + bv.x, 0.f) * wv.x
                     + fmaxf(accB[m][n][1] + bv.y, 0.f) * wv.y
                     + fmaxf(accB[m][n][2] + bv.z, 0.f) * wv.z
                     + fmaxf(accB[m][n][3] + bv.w, 0.f) * wv.w;
        }
    }
#pragma unroll
    for (int m = 0; m < 2; ++m) {
        float v = part[m];
        v += __shfl_xor(v, 16, 64);
        v += __shfl_xor(v, 32, 64);
        if (lane < 16) red[wc * 64 + wr * 32 + m * 16 + fr] = v;
    }
    __syncthreads();
    if (t < 64) {
        const float sm = red[t] + red[64 + t] + red[128 + t] + red[192 + t];
        out[bBase + t] = 1.f / (1.f + expf(-(sm + tb2[0])));
    }
}

extern "C" void kernel_launch(void* const* d_in, const int* in_sizes, int n_in,
                              void* d_out, int out_size, void* d_ws, size_t ws_size,
                              hipStream_t stream)
{
    (void)in_sizes; (void)n_in; (void)out_size; (void)ws_size;
    const float* dense_x = (const float*)d_in[0];
    const int*   indices = (const int*)d_in[1];
    const float* emb     = (const float*)d_in[2];
    const float* bw0 = (const float*)d_in[3];
    const float* bb0 = (const float*)d_in[4];
    const float* bw1 = (const float*)d_in[5];
    const float* bb1 = (const float*)d_in[6];
    const float* bw2 = (const float*)d_in[7];
    const float* bb2 = (const float*)d_in[8];
    const float* tw0 = (const float*)d_in[9];
    const float* tb0 = (const float*)d_in[10];
    const float* tw1 = (const float*)d_in[11];
    const float* tb1 = (const float*)d_in[12];
    const float* tw2 = (const float*)d_in[13];
    const float* tb2 = (const float*)d_in[14];
    float* out = (float*)d_out;

    ushort* ws16      = (ushort*)d_ws;
    ushort* dense_pad = ws16;                              // B x 32
    ushort* bw0p      = dense_pad + (size_t)B_SZ * 32;     // 512 x 32
    ushort* tw0p      = bw0p + 512 * 32;                   // 512 x 416
    ushort* bw1c      = tw0p + 512 * 416;                  // 256 x 512
    ushort* bw2c      = bw1c + 256 * 512;                  // 64 x 256
    ushort* tw1c      = bw2c + 64 * 256;                   // 256 x 512

    conv_all_k<<<dim3(6080), dim3(256), 0, stream>>>(
        dense_x, bw0, tw0, bw1, bw2, tw1,
        dense_pad, bw0p, tw0p, bw1c, bw2c, tw1c);

    fused_k<<<dim3(B_SZ / 64), dim3(512), 0, stream>>>(
        dense_pad, bw0p, bb0, bw1c, bb1, bw2c, bb2,
        emb, indices, tw0p, tb0, tw1c, tb1, tw2, tb2, out);
}

// Round 15
// 108.512 us; speedup vs baseline: 1.4878x; 1.0723x over previous
//
#include <hip/hip_runtime.h>
#include <cstddef>
#include <cstdint>

#define B_SZ    32768
#define NTAB    26
#define NROWS   200000

typedef __attribute__((ext_vector_type(8))) short short8v;
typedef __attribute__((ext_vector_type(4))) float f32x4;
typedef __attribute__((ext_vector_type(16))) float f32x16;

__device__ __forceinline__ ushort f2bf(float f) {
    uint32_t u = __builtin_bit_cast(uint32_t, f);
    u += 0x7FFFu + ((u >> 16) & 1u);
    return (ushort)(u >> 16);
}
__device__ __forceinline__ void stage16(const ushort* g, ushort* l) {
    __builtin_amdgcn_global_load_lds(
        (const __attribute__((address_space(1))) unsigned int*)g,
        (__attribute__((address_space(3))) unsigned int*)l, 16, 0, 0);
}

// All fp32->bf16 conversions (with K->Kp zero pad) in ONE kernel.
__global__ __launch_bounds__(256) void conv_all_k(
    const float* __restrict__ dense_x, const float* __restrict__ bw0,
    const float* __restrict__ tw0, const float* __restrict__ bw1,
    const float* __restrict__ bw2, const float* __restrict__ tw1,
    ushort* __restrict__ dense_pad, ushort* __restrict__ bw0p,
    ushort* __restrict__ tw0p, ushort* __restrict__ bw1c,
    ushort* __restrict__ bw2c, ushort* __restrict__ tw1c)
{
    const int gid = blockIdx.x * 256 + threadIdx.x;
    if (gid < 1048576) {
        int r = gid >> 5, k = gid & 31;
        dense_pad[gid] = (k < 13) ? f2bf(dense_x[r * 13 + k]) : (ushort)0;
    } else if (gid < 1064960) {
        int i = gid - 1048576; int r = i >> 5, k = i & 31;
        bw0p[i] = (k < 13) ? f2bf(bw0[r * 13 + k]) : (ushort)0;
    } else if (gid < 1277952) {
        int i = gid - 1064960; int r = i / 416, k = i - r * 416;
        tw0p[i] = (k < 415) ? f2bf(tw0[r * 415 + k]) : (ushort)0;
    } else if (gid < 1409024) {
        int i = gid - 1277952; bw1c[i] = f2bf(bw1[i]);
    } else if (gid < 1425408) {
        int i = gid - 1409024; bw2c[i] = f2bf(bw2[i]);
    } else if (gid < 1556480) {
        int i = gid - 1425408; tw1c[i] = f2bf(tw1[i]);
    }
}

// ---------------------------------------------------------------------------
// FULLY FUSED per-32-sample pipeline (R12 geometry: 256 thr, 2 blocks/CU):
//   bot 13(->32)->512->256->64 | gather+Gram (32x32x16, A==B) | top 415->512->256->sigmoid
// Changes vs R12: P2 staged in ONE 32KB drain (barrier-free P2 K-loop);
// Gram gather is branch-free with 2-deep register pipelining.
// LDS 80 KB: R1(32K) = h0s|Rt|th0s; Wst 32K; R3(16K) = dense|h1s|scratch.
// ---------------------------------------------------------------------------
__global__ __launch_bounds__(256, 2) void fused_k(
    const ushort* __restrict__ dense_pad, const ushort* __restrict__ bw0p,
    const float* __restrict__ bb0, const ushort* __restrict__ bw1c,
    const float* __restrict__ bb1, const ushort* __restrict__ bw2c,
    const float* __restrict__ bb2,
    const float* __restrict__ emb, const int* __restrict__ indices,
    const ushort* __restrict__ tw0p, const float* __restrict__ tb0,
    const ushort* __restrict__ tw1c, const float* __restrict__ tb1,
    const float* __restrict__ tw2, const float* __restrict__ tb2,
    float* __restrict__ out)
{
    __shared__ __align__(16) ushort R1[32 * 512];      // 32 KB
    __shared__ __align__(16) ushort Wst[2][256 * 32];  // 2 x 16 KB (contiguous)
    __shared__ __align__(16) ushort R3[32 * 256];      // 16 KB
    ushort* const Wf = &Wst[0][0];
    const int t = threadIdx.x;
    const int lane = t & 63, w = t >> 6;
    const int fr = lane & 15, j16 = lane >> 4;
    const int bBase = blockIdx.x * 32;

    // index loads to REGISTERS now; latency hides under the bottom MLP
    int ir0, ir1, ir2, ir3;
    ir0 = indices[(size_t)(t >> 5) * B_SZ + bBase + (t & 31)];
    ir1 = indices[(size_t)((256 + t) >> 5) * B_SZ + bBase + ((256 + t) & 31)];
    ir2 = indices[(size_t)((512 + t) >> 5) * B_SZ + bBase + ((512 + t) & 31)];
    ir3 = (t < 64) ? indices[(size_t)((768 + t) >> 5) * B_SZ + bBase + ((768 + t) & 31)] : 0;

    // prologue: dense tile -> R3; all of bw0p (32 KB) -> Wst
    if (t < 128) {
        const int r = t >> 2, u = t & 3, us = u ^ ((r >> 1) & 3);
        stage16(dense_pad + (size_t)(bBase + r) * 32 + us * 8, &R3[t * 8]);
    }
#pragma unroll
    for (int i = 0; i < 4; ++i) {
        const int idx = i * 256 + t;
        const int r = idx >> 2, u = idx & 3, us = u ^ ((r >> 1) & 3);
        stage16(bw0p + (size_t)r * 32 + us * 8, &Wst[0][idx * 8]);
        stage16(bw0p + (size_t)(256 + r) * 32 + us * 8, &Wst[1][idx * 8]);
    }
    __syncthreads();

    // P0: h0 = relu(dense @ bw0^T + bb0), K=32, both channel halves
    f32x4 acc0[2][2][4] = {};
    {
        short8v a[2];
#pragma unroll
        for (int m = 0; m < 2; ++m) {
            const int r = m * 16 + fr;
            a[m] = *(const short8v*)&R3[r * 32 + (j16 ^ ((r >> 1) & 3)) * 8];
        }
#pragma unroll
        for (int hh = 0; hh < 2; ++hh) {
            short8v b[4];
#pragma unroll
            for (int n = 0; n < 4; ++n) {
                const int lr = w * 64 + n * 16 + fr;
                b[n] = *(const short8v*)&Wst[hh][lr * 32 + (j16 ^ ((lr >> 1) & 3)) * 8];
            }
            __builtin_amdgcn_s_setprio(1);
#pragma unroll
            for (int m = 0; m < 2; ++m)
#pragma unroll
                for (int n = 0; n < 4; ++n)
                    acc0[hh][m][n] = __builtin_amdgcn_mfma_f32_16x16x32_bf16(b[n], a[m], acc0[hh][m][n], 0, 0, 0);
            __builtin_amdgcn_s_setprio(0);
        }
    }
    __syncthreads();

    // pre-stage P1 pair; latency hides under P0 epilogue
#pragma unroll
    for (int i = 0; i < 4; ++i) {
        const int idx = i * 256 + t;
        const int r = idx >> 2, u = idx & 3, us = u ^ ((r >> 1) & 3);
        stage16(bw1c + (size_t)r * 512 + us * 8, &Wst[0][idx * 8]);
        stage16(bw1c + (size_t)r * 512 + 32 + us * 8, &Wst[1][idx * 8]);
    }
    // P0 epilogue -> R1 as h0s (stride 512, swizzle by sample&7)
#pragma unroll
    for (int hh = 0; hh < 2; ++hh)
#pragma unroll
    for (int n = 0; n < 4; ++n) {
        const int ch = hh * 256 + w * 64 + n * 16 + j16 * 4;
        const float4 bv = *(const float4*)&bb0[ch];
#pragma unroll
        for (int m = 0; m < 2; ++m) {
            const int s = m * 16 + fr;
            ushort4 o;
            o.x = f2bf(fmaxf(acc0[hh][m][n][0] + bv.x, 0.f));
            o.y = f2bf(fmaxf(acc0[hh][m][n][1] + bv.y, 0.f));
            o.z = f2bf(fmaxf(acc0[hh][m][n][2] + bv.z, 0.f));
            o.w = f2bf(fmaxf(acc0[hh][m][n][3] + bv.w, 0.f));
            const int u = ch >> 3, su = u ^ (s & 7);
            *(ushort4*)&R1[s * 512 + su * 8 + (ch & 7)] = o;
        }
    }
    __syncthreads();

    // P1: h1 = relu(h0 @ bw1^T + bb1), K=512, 8 iters x 64k, double-wide staged
    f32x4 acc1[2][4] = {};
    for (int i8 = 0; i8 < 8; ++i8) {
#pragma unroll
        for (int half = 0; half < 2; ++half) {
            const int kt = i8 * 64 + half * 32;
            short8v a[2], b[4];
#pragma unroll
            for (int m = 0; m < 2; ++m) {
                const int s = m * 16 + fr;
                const int u = (kt >> 3) + j16, su = u ^ (s & 7);
                a[m] = *(const short8v*)&R1[s * 512 + su * 8];
            }
#pragma unroll
            for (int n = 0; n < 4; ++n) {
                const int lr = w * 64 + n * 16 + fr;
                b[n] = *(const short8v*)&Wst[half][lr * 32 + (j16 ^ ((lr >> 1) & 3)) * 8];
            }
            __builtin_amdgcn_s_setprio(1);
#pragma unroll
            for (int m = 0; m < 2; ++m)
#pragma unroll
                for (int n = 0; n < 4; ++n)
                    acc1[m][n] = __builtin_amdgcn_mfma_f32_16x16x32_bf16(b[n], a[m], acc1[m][n], 0, 0, 0);
            __builtin_amdgcn_s_setprio(0);
        }
        __syncthreads();
        if (i8 < 7) {
            const int kt2 = (i8 + 1) * 64;
#pragma unroll
            for (int i = 0; i < 4; ++i) {
                const int idx = i * 256 + t;
                const int r = idx >> 2, u = idx & 3, us = u ^ ((r >> 1) & 3);
                stage16(bw1c + (size_t)r * 512 + kt2 + us * 8, &Wst[0][idx * 8]);
                stage16(bw1c + (size_t)r * 512 + kt2 + 32 + us * 8, &Wst[1][idx * 8]);
            }
            __syncthreads();
        }
    }
    // pre-stage ALL of bw2c (32 KB, 8 K-subtiles) in ONE drain
#pragma unroll
    for (int i = 0; i < 8; ++i) {
        const int idx = i * 256 + t;                 // 0..2047
        const int st = idx >> 8, within = idx & 255;
        const int r = within >> 2, u = within & 3, us = u ^ ((r >> 1) & 3);
        stage16(bw2c + (size_t)r * 256 + st * 32 + us * 8, &Wf[idx * 8]);
    }
    // P1 epilogue -> R3 as h1s (stride 256, swizzle)
#pragma unroll
    for (int n = 0; n < 4; ++n) {
        const int ch = w * 64 + n * 16 + j16 * 4;
        const float4 bv = *(const float4*)&bb1[ch];
#pragma unroll
        for (int m = 0; m < 2; ++m) {
            const int s = m * 16 + fr;
            ushort4 o;
            o.x = f2bf(fmaxf(acc1[m][n][0] + bv.x, 0.f));
            o.y = f2bf(fmaxf(acc1[m][n][1] + bv.y, 0.f));
            o.z = f2bf(fmaxf(acc1[m][n][2] + bv.z, 0.f));
            o.w = f2bf(fmaxf(acc1[m][n][3] + bv.w, 0.f));
            const int u = ch >> 3, su = u ^ (s & 7);
            *(ushort4*)&R3[s * 256 + su * 8 + (ch & 7)] = o;
        }
    }
    __syncthreads();

    // P2: x_bot = relu(h1 @ bw2^T + bb2), K=256 -- BARRIER-FREE (all weights resident)
    f32x4 acc2[2] = {};
    for (int kt = 0; kt < 256; kt += 32) {
        short8v a[2], b;
#pragma unroll
        for (int m = 0; m < 2; ++m) {
            const int s = m * 16 + fr;
            const int u = (kt >> 3) + j16, su = u ^ (s & 7);
            a[m] = *(const short8v*)&R3[s * 256 + su * 8];
        }
        {
            const int lr = w * 16 + fr;
            b = *(const short8v*)&Wf[(kt >> 5) * 2048 + lr * 32 + (j16 ^ ((lr >> 1) & 3)) * 8];
        }
#pragma unroll
        for (int m = 0; m < 2; ++m)
            acc2[m] = __builtin_amdgcn_mfma_f32_16x16x32_bf16(b, a[m], acc2[m], 0, 0, 0);
    }
    __syncthreads();   // all waves done with Wf + h1s

    // P2 epilogue: pre-stage top-A kt=0 pair; x_bot -> R1 Rt[:, 0:64]; indices -> R3
#pragma unroll
    for (int i = 0; i < 4; ++i) {
        const int idx = i * 256 + t;
        const int r = idx >> 2, u = idx & 3, us = u ^ ((r >> 1) & 3);
        stage16(tw0p + (size_t)r * 416 + us * 8, &Wst[0][idx * 8]);
        stage16(tw0p + (size_t)(256 + r) * 416 + us * 8, &Wst[1][idx * 8]);
    }
    {
        const int ch = w * 16 + j16 * 4;
        const float4 bv = *(const float4*)&bb2[ch];
#pragma unroll
        for (int m = 0; m < 2; ++m) {
            const int s = m * 16 + fr;
            ushort4 o;
            o.x = f2bf(fmaxf(acc2[m][0] + bv.x, 0.f));
            o.y = f2bf(fmaxf(acc2[m][1] + bv.y, 0.f));
            o.z = f2bf(fmaxf(acc2[m][2] + bv.z, 0.f));
            o.w = f2bf(fmaxf(acc2[m][3] + bv.w, 0.f));
            *(ushort4*)&R1[s * 424 + ch] = o;
        }
    }
    if (t < 32) R1[t * 424 + 415] = 0;
    {
        int* sc = (int*)R3;
        sc[t] = ir0; sc[256 + t] = ir1; sc[512 + t] = ir2;
        if (t < 64) sc[768 + t] = ir3;
    }
    __syncthreads();

    // Gram: Z = T.T^T via 32x32x16 MFMA (A==B). Branch-free loads (clamped
    // addresses, values fixed by select) + 2-deep register pipeline.
    {
        const int* sc = (const int*)R3;
        const int r32 = lane & 31, half = lane >> 5;
        const bool isEmb = (r32 >= 1) && (r32 <= 26);
        const size_t tblOfs = isEmb ? (size_t)(r32 - 1) * NROWS : 0;

#define LOADRAW(dst, s_) { \
        const int idxv = isEmb ? sc[(r32 - 1) * 32 + (s_)] : 0; \
        const float* rp = emb + (tblOfs + (size_t)idxv) * 64 + half * 8; \
        _Pragma("unroll") \
        for (int kq = 0; kq < 4; ++kq) { \
            dst[2 * kq]     = *(const f32x4*)&rp[kq * 16]; \
            dst[2 * kq + 1] = *(const f32x4*)&rp[kq * 16 + 4]; } }

#define COMPUTE(raw, s_) { \
        short8v tf[4]; \
        _Pragma("unroll") \
        for (int kq = 0; kq < 4; ++kq) { \
            short8v v; \
            v[0] = (short)f2bf(raw[2 * kq][0]);     v[1] = (short)f2bf(raw[2 * kq][1]); \
            v[2] = (short)f2bf(raw[2 * kq][2]);     v[3] = (short)f2bf(raw[2 * kq][3]); \
            v[4] = (short)f2bf(raw[2 * kq + 1][0]); v[5] = (short)f2bf(raw[2 * kq + 1][1]); \
            v[6] = (short)f2bf(raw[2 * kq + 1][2]); v[7] = (short)f2bf(raw[2 * kq + 1][3]); \
            if (r32 == 0) v = *(const short8v*)&R1[(s_) * 424 + kq * 16 + half * 8]; \
            else if (!isEmb) v = (short8v)0; \
            tf[kq] = v; } \
        f32x16 c = {}; \
        _Pragma("unroll") \
        for (int kq = 0; kq < 4; ++kq) \
            c = __builtin_amdgcn_mfma_f32_32x32x16_bf16(tf[kq], tf[kq], c, 0, 0, 0); \
        _Pragma("unroll") \
        for (int reg = 0; reg < 16; ++reg) { \
            const int r = (reg & 3) + 8 * (reg >> 2) + 4 * half; \
            if (r < 27 && r32 < r) \
                R1[(s_) * 424 + 64 + (r * (r - 1)) / 2 + r32] = f2bf(c[reg]); } }

        f32x4 rawA[8], rawB[8];
        LOADRAW(rawA, w);
#pragma unroll
        for (int p = 0; p < 4; ++p) {
            const int sA = p * 8 + w;
            const int sB = p * 8 + 4 + w;
            LOADRAW(rawB, sB);
            COMPUTE(rawA, sA);
            if (p < 3) LOADRAW(rawA, p * 8 + 8 + w);
            COMPUTE(rawB, sB);
        }
#undef LOADRAW
#undef COMPUTE
    }
    __syncthreads();

    // phase A: th0 = relu(R @ tw0^T + tb0), K=416, 13 iters (both ch-halves)
    f32x4 accA[2][2][4] = {};
    for (int kt_i = 0; kt_i < 13; ++kt_i) {
        const int kt = kt_i * 32;
        short8v a[2];
#pragma unroll
        for (int m = 0; m < 2; ++m) {
            const int s = m * 16 + fr;
            a[m] = *(const short8v*)&R1[s * 424 + ((kt >> 3) + j16) * 8];
        }
#pragma unroll
        for (int hh = 0; hh < 2; ++hh) {
            short8v b[4];
#pragma unroll
            for (int n = 0; n < 4; ++n) {
                const int lr = w * 64 + n * 16 + fr;
                b[n] = *(const short8v*)&Wst[hh][lr * 32 + (j16 ^ ((lr >> 1) & 3)) * 8];
            }
            __builtin_amdgcn_s_setprio(1);
#pragma unroll
            for (int m = 0; m < 2; ++m)
#pragma unroll
                for (int n = 0; n < 4; ++n)
                    accA[hh][m][n] = __builtin_amdgcn_mfma_f32_16x16x32_bf16(b[n], a[m], accA[hh][m][n], 0, 0, 0);
            __builtin_amdgcn_s_setprio(0);
        }
        __syncthreads();
        if (kt_i < 12) {
            const int kt2 = kt + 32;
#pragma unroll
            for (int i = 0; i < 4; ++i) {
                const int idx = i * 256 + t;
                const int r = idx >> 2, u = idx & 3, us = u ^ ((r >> 1) & 3);
                stage16(tw0p + (size_t)r * 416 + kt2 + us * 8, &Wst[0][idx * 8]);
                stage16(tw0p + (size_t)(256 + r) * 416 + kt2 + us * 8, &Wst[1][idx * 8]);
            }
            __syncthreads();
        }
    }
    // pre-stage phase-B pair (tw1c kt=0 -> Wst[0], kt=32 -> Wst[1])
#pragma unroll
    for (int i = 0; i < 4; ++i) {
        const int idx = i * 256 + t;
        const int r = idx >> 2, u = idx & 3, us = u ^ ((r >> 1) & 3);
        stage16(tw1c + (size_t)r * 512 + us * 8, &Wst[0][idx * 8]);
        stage16(tw1c + (size_t)r * 512 + 32 + us * 8, &Wst[1][idx * 8]);
    }
    // phase A epilogue: th0s into R1 (stride 512; Rt dead)
#pragma unroll
    for (int hh = 0; hh < 2; ++hh)
#pragma unroll
    for (int n = 0; n < 4; ++n) {
        const int ch = hh * 256 + w * 64 + n * 16 + j16 * 4;
        const float4 bv = *(const float4*)&tb0[ch];
#pragma unroll
        for (int m = 0; m < 2; ++m) {
            const int s = m * 16 + fr;
            ushort4 o;
            o.x = f2bf(fmaxf(accA[hh][m][n][0] + bv.x, 0.f));
            o.y = f2bf(fmaxf(accA[hh][m][n][1] + bv.y, 0.f));
            o.z = f2bf(fmaxf(accA[hh][m][n][2] + bv.z, 0.f));
            o.w = f2bf(fmaxf(accA[hh][m][n][3] + bv.w, 0.f));
            const int u = ch >> 3, su = u ^ (s & 7);
            *(ushort4*)&R1[s * 512 + su * 8 + (ch & 7)] = o;
        }
    }
    __syncthreads();

    // phase B: th1 = relu(th0 @ tw1^T + tb1), K=512, 8 iters x 64k
    f32x4 accB[2][4] = {};
    for (int i8 = 0; i8 < 8; ++i8) {
#pragma unroll
        for (int half = 0; half < 2; ++half) {
            const int kt = i8 * 64 + half * 32;
            short8v a[2], b[4];
#pragma unroll
            for (int m = 0; m < 2; ++m) {
                const int s = m * 16 + fr;
                const int u = (kt >> 3) + j16, su = u ^ (s & 7);
                a[m] = *(const short8v*)&R1[s * 512 + su * 8];
            }
#pragma unroll
            for (int n = 0; n < 4; ++n) {
                const int lr = w * 64 + n * 16 + fr;
                b[n] = *(const short8v*)&Wst[half][lr * 32 + (j16 ^ ((lr >> 1) & 3)) * 8];
            }
            __builtin_amdgcn_s_setprio(1);
#pragma unroll
            for (int m = 0; m < 2; ++m)
#pragma unroll
                for (int n = 0; n < 4; ++n)
                    accB[m][n] = __builtin_amdgcn_mfma_f32_16x16x32_bf16(b[n], a[m], accB[m][n], 0, 0, 0);
            __builtin_amdgcn_s_setprio(0);
        }
        __syncthreads();
        if (i8 < 7) {
            const int kt2 = (i8 + 1) * 64;
#pragma unroll
            for (int i = 0; i < 4; ++i) {
                const int idx = i * 256 + t;
                const int r = idx >> 2, u = idx & 3, us = u ^ ((r >> 1) & 3);
                stage16(tw1c + (size_t)r * 512 + kt2 + us * 8, &Wst[0][idx * 8]);
                stage16(tw1c + (size_t)r * 512 + kt2 + 32 + us * 8, &Wst[1][idx * 8]);
            }
            __syncthreads();
        }
    }

    // phase C: out = sigmoid( relu(th1) . tw2 + tb2 )
    float* red = (float*)R3;
    float part[2] = {0.f, 0.f};
#pragma unroll
    for (int n = 0; n < 4; ++n) {
        const int ch = w * 64 + n * 16 + j16 * 4;
        const float4 bv = *(const float4*)&tb1[ch];
        const float4 wv = *(const float4*)&tw2[ch];
#pragma unroll
        for (int m = 0; m < 2; ++m) {
            part[m] += fmaxf(accB[m][n][0] + bv.x, 0.f) * wv.x
                     + fmaxf(accB[m][n][1] + bv.y, 0.f) * wv.y
                     + fmaxf(accB[m][n][2] + bv.z, 0.f) * wv.z
                     + fmaxf(accB[m][n][3] + bv.w, 0.f) * wv.w;
        }
    }
#pragma unroll
    for (int m = 0; m < 2; ++m) {
        float v = part[m];
        v += __shfl_xor(v, 16, 64);
        v += __shfl_xor(v, 32, 64);
        if (lane < 16) red[w * 32 + m * 16 + fr] = v;
    }
    __syncthreads();
    if (t < 32) {
        const float sm = red[t] + red[32 + t] + red[64 + t] + red[96 + t];
        out[bBase + t] = 1.f / (1.f + expf(-(sm + tb2[0])));
    }
}

extern "C" void kernel_launch(void* const* d_in, const int* in_sizes, int n_in,
                              void* d_out, int out_size, void* d_ws, size_t ws_size,
                              hipStream_t stream)
{
    (void)in_sizes; (void)n_in; (void)out_size; (void)ws_size;
    const float* dense_x = (const float*)d_in[0];
    const int*   indices = (const int*)d_in[1];
    const float* emb     = (const float*)d_in[2];
    const float* bw0 = (const float*)d_in[3];
    const float* bb0 = (const float*)d_in[4];
    const float* bw1 = (const float*)d_in[5];
    const float* bb1 = (const float*)d_in[6];
    const float* bw2 = (const float*)d_in[7];
    const float* bb2 = (const float*)d_in[8];
    const float* tw0 = (const float*)d_in[9];
    const float* tb0 = (const float*)d_in[10];
    const float* tw1 = (const float*)d_in[11];
    const float* tb1 = (const float*)d_in[12];
    const float* tw2 = (const float*)d_in[13];
    const float* tb2 = (const float*)d_in[14];
    float* out = (float*)d_out;

    ushort* ws16      = (ushort*)d_ws;
    ushort* dense_pad = ws16;                              // B x 32
    ushort* bw0p      = dense_pad + (size_t)B_SZ * 32;     // 512 x 32
    ushort* tw0p      = bw0p + 512 * 32;                   // 512 x 416
    ushort* bw1c      = tw0p + 512 * 416;                  // 256 x 512
    ushort* bw2c      = bw1c + 256 * 512;                  // 64 x 256
    ushort* tw1c      = bw2c + 64 * 256;                   // 256 x 512

    conv_all_k<<<dim3(6080), dim3(256), 0, stream>>>(
        dense_x, bw0, tw0, bw1, bw2, tw1,
        dense_pad, bw0p, tw0p, bw1c, bw2c, tw1c);

    fused_k<<<dim3(B_SZ / 32), dim3(256), 0, stream>>>(
        dense_pad, bw0p, bb0, bw1c, bb1, bw2c, bb2,
        emb, indices, tw0p, tb0, tw1c, tb1, tw2, tb2, out);
}